// Round 5
// baseline (535.477 us; speedup 1.0000x reference)
//
#include <hip/hip_runtime.h>
#include <hip/hip_bf16.h>
#include <math.h>

// Problem constants (from reference setup_inputs)
#define BN  8
#define QN  2048
#define KN  2048
#define FN  512
#define FVN 512

typedef __bf16 bf16x8 __attribute__((ext_vector_type(8)));
typedef __bf16 bf16x4v __attribute__((ext_vector_type(4)));
typedef float  f32x4  __attribute__((ext_vector_type(4)));

__device__ inline bf16x8 pack8(float4 a, float4 b) {
  bf16x8 r;
  r[0] = (__bf16)a.x; r[1] = (__bf16)a.y; r[2] = (__bf16)a.z; r[3] = (__bf16)a.w;
  r[4] = (__bf16)b.x; r[5] = (__bf16)b.y; r[6] = (__bf16)b.z; r[7] = (__bf16)b.w;
  return r;
}

// Async global->LDS, 16B/lane. LDS dest = wave-uniform base + lane*16 (m97).
__device__ __forceinline__ void g2l16(const __bf16* g, __bf16* l) {
  __builtin_amdgcn_global_load_lds(
      (const __attribute__((address_space(1))) void*)g,
      (__attribute__((address_space(3))) void*)l,
      16, 0, 0);
}

// ---------------------------------------------------------------------------
// Kernel 0 (prep): y==0 -> q convert (pre-scaled), y==1 -> k convert,
//                  y==2 -> v transpose to Vt[b, fv, k] bf16.
// ---------------------------------------------------------------------------
__global__ __launch_bounds__(256) void prep(
    const float* __restrict__ qm, const float* __restrict__ km,
    const float* __restrict__ vm,
    __bf16* __restrict__ qb, __bf16* __restrict__ kb, __bf16* __restrict__ Vt) {
  const int tid = threadIdx.x;
  if (blockIdx.y == 0) {
    const size_t idx = ((size_t)blockIdx.x * 256 + tid) * 8;
    const float scale = 0.044194173824159216f;  // 512^-0.5
    float4 a = *(const float4*)(qm + idx);
    float4 b = *(const float4*)(qm + idx + 4);
    a.x *= scale; a.y *= scale; a.z *= scale; a.w *= scale;
    b.x *= scale; b.y *= scale; b.z *= scale; b.w *= scale;
    *(bf16x8*)(qb + idx) = pack8(a, b);
  } else if (blockIdx.y == 1) {
    const size_t idx = ((size_t)blockIdx.x * 256 + tid) * 8;
    float4 a = *(const float4*)(km + idx);
    float4 b = *(const float4*)(km + idx + 4);
    *(bf16x8*)(kb + idx) = pack8(a, b);
  } else {
    // v transpose: bx = ((b*8)+fblk)*32 + kblk
    const int bx = blockIdx.x;
    if (bx >= (KN / 64) * (FVN / 64) * BN) return;
    const int b  = bx >> 8;
    const int f0 = ((bx >> 5) & 7) * 64;
    const int k0 = (bx & 31) * 64;
    __shared__ float tile[64][65];
    const int r = tid >> 4;          // 0..15
    const int c = (tid & 15) * 4;    // 0..60
#pragma unroll
    for (int i = 0; i < 4; i++) {
      float4 u = *(const float4*)(vm + ((size_t)b * KN + k0 + r + i * 16) * FVN + f0 + c);
      tile[r + i * 16][c] = u.x; tile[r + i * 16][c + 1] = u.y;
      tile[r + i * 16][c + 2] = u.z; tile[r + i * 16][c + 3] = u.w;
    }
    __syncthreads();
#pragma unroll
    for (int i = 0; i < 4; i++) {
      int fv = r + i * 16;
      bf16x4v w;
      w[0] = (__bf16)tile[c][fv];     w[1] = (__bf16)tile[c + 1][fv];
      w[2] = (__bf16)tile[c + 2][fv]; w[3] = (__bf16)tile[c + 3][fv];
      *(bf16x4v*)(Vt + ((size_t)b * FVN + f0 + fv) * KN + k0 + c) = w;
    }
  }
}

// ---------------------------------------------------------------------------
// Kernel 1: S[z,q,k] = (bf16) dot(qb[b,q,:], kb[b,k,:])   (scale pre-folded)
// 128x128 tile, BK=64 (two [128][32] LDS half-tiles, g2l16 staging).
// Epilogue: per-row partial sum_k exp(bf16(S)) -> atomicAdd into sums.
// ---------------------------------------------------------------------------
__global__ __launch_bounds__(256) void gemm_s(
    const __bf16* __restrict__ qb, const __bf16* __restrict__ kb,
    __bf16* __restrict__ Sws, float* __restrict__ sums,
    int b0, int q0, int qchunk) {
  __shared__ __align__(16) __bf16 As[2][128][32];
  __shared__ __align__(16) __bf16 Bs[2][128][32];
  const int tid = threadIdx.x;
  const int lane = tid & 63, wave = tid >> 6;
  const int wq = (wave & 1) * 64, wk = (wave >> 1) * 64;
  const int qt = blockIdx.x * 128, kt = blockIdx.y * 128;
  const int z = blockIdx.z, b = b0 + z;
  __bf16* S = Sws + (size_t)z * qchunk * KN;
  const __bf16* Ab = qb + ((size_t)b * QN + q0 + qt) * FN;
  const __bf16* Bb = kb + ((size_t)b * KN + kt) * FN;
  const int srow = lane >> 2;         // 0..15 within 16-row group
  const int scol = (lane & 3) * 8;    // bf16 col within 32
  const int r = lane & 15, quad = lane >> 4;
  f32x4 acc[4][4] = {};
  for (int f0 = 0; f0 < FN; f0 += 64) {
    __syncthreads();
#pragma unroll
    for (int h = 0; h < 2; h++) {
      const int co = f0 + h * 32 + scol;
      g2l16(Ab + (size_t)(wave * 32 + srow) * FN + co,      &As[h][wave * 32][0]);
      g2l16(Ab + (size_t)(wave * 32 + 16 + srow) * FN + co, &As[h][wave * 32 + 16][0]);
      g2l16(Bb + (size_t)(wave * 32 + srow) * FN + co,      &Bs[h][wave * 32][0]);
      g2l16(Bb + (size_t)(wave * 32 + 16 + srow) * FN + co, &Bs[h][wave * 32 + 16][0]);
    }
    __syncthreads();
#pragma unroll
    for (int h = 0; h < 2; h++) {
      bf16x8 af[4], bf[4];
#pragma unroll
      for (int i = 0; i < 4; i++) af[i] = *(bf16x8*)&As[h][wq + i * 16 + r][quad * 8];
#pragma unroll
      for (int j = 0; j < 4; j++) bf[j] = *(bf16x8*)&Bs[h][wk + j * 16 + r][quad * 8];
#pragma unroll
      for (int i = 0; i < 4; i++)
#pragma unroll
        for (int j = 0; j < 4; j++)
          acc[i][j] = __builtin_amdgcn_mfma_f32_16x16x32_bf16(af[i], bf[j], acc[i][j], 0, 0, 0);
    }
  }
  // C/D layout: col = lane&15 (=k), row = quad*4+reg (=q). Write S (bf16) and
  // accumulate per-row sum of exp over this block's 64 k-columns (wave-local).
#pragma unroll
  for (int i = 0; i < 4; i++)
#pragma unroll
    for (int t = 0; t < 4; t++) {
      float e = 0.f;
#pragma unroll
      for (int j = 0; j < 4; j++) {
        __bf16 sb = (__bf16)acc[i][j][t];
        S[(size_t)(qt + wq + i * 16 + quad * 4 + t) * KN + (kt + wk + j * 16 + r)] = sb;
        e += __expf((float)sb);
      }
      // reduce over r (lanes sharing same row within the quad)
      e += __shfl_xor(e, 1); e += __shfl_xor(e, 2);
      e += __shfl_xor(e, 4); e += __shfl_xor(e, 8);
      if (r == 0)
        atomicAdd(&sums[(size_t)z * qchunk + qt + wq + i * 16 + quad * 4 + t], e);
    }
}

// ---------------------------------------------------------------------------
// Kernel 2 (fused): out[b,q,fv] = sum_k W[q,k] * Vt[fv,k]
//   W = attn ? 0 : (exp(S)/sums[q] - (alibi ? 0 : dist(q,k)*bias_scale))
// Block = 64q x 512fv, BK=32; wave w owns fv [w*128, w*128+128), all 64 q.
// W computed in registers -> LDS; V staged via g2l16. Masks read exactly once.
// ---------------------------------------------------------------------------
__global__ __launch_bounds__(256) void gemm_wv(
    const __bf16* __restrict__ S, const float* __restrict__ sums,
    const __bf16* __restrict__ Vt,
    const float* __restrict__ cq, const float* __restrict__ ck,
    const int* __restrict__ attn, const int* __restrict__ alibi,
    const float* __restrict__ bsp, float* __restrict__ out,
    int b0, int q0, int qchunk) {
  __shared__ __align__(16) __bf16 Ws[64][32];    // [q][k]   4 KB
  __shared__ __align__(16) __bf16 Vs[512][32];   // [fv][k] 32 KB
  const int tid = threadIdx.x;
  const int lane = tid & 63, wave = tid >> 6;
  const int qt = blockIdx.x * 64;
  const int z = blockIdx.z, b = b0 + z;
  const int wr = tid >> 2;          // W row 0..63 (q local)
  const int wc = (tid & 3) * 8;     // W col chunk (k offset in tile)
  const int qg = q0 + qt + wr;
  const float qx = cq[((size_t)b * QN + qg) * 2 + 0];
  const float qy = cq[((size_t)b * QN + qg) * 2 + 1];
  const float inv = 1.0f / sums[(size_t)z * qchunk + qt + wr];
  const float bs = bsp[0];
  const __bf16* Srow = S + ((size_t)z * qchunk + qt + wr) * KN;
  const int* arow = attn + ((size_t)b * QN + qg) * KN;
  const int* lrow = alibi + ((size_t)b * QN + qg) * KN;
  const float* ckb = ck + (size_t)b * KN * 2;
  const __bf16* Vb = Vt + ((size_t)b * FVN + wave * 128) * KN;
  const int srow = lane >> 2, scol = (lane & 3) * 8;
  const int r = lane & 15, quad = lane >> 4;
  f32x4 acc[4][8] = {};
  for (int k0 = 0; k0 < KN; k0 += 32) {
    // --- W ingredients (global, before barrier: overlaps prev MFMA phase) ---
    bf16x8 s8 = *(const bf16x8*)(Srow + k0 + wc);
    int4 am0 = *(const int4*)(arow + k0 + wc);
    int4 am1 = *(const int4*)(arow + k0 + wc + 4);
    int4 al0 = *(const int4*)(lrow + k0 + wc);
    int4 al1 = *(const int4*)(lrow + k0 + wc + 4);
    float4 c0 = *(const float4*)(ckb + (size_t)(k0 + wc) * 2);
    float4 c1 = *(const float4*)(ckb + (size_t)(k0 + wc) * 2 + 4);
    float4 c2 = *(const float4*)(ckb + (size_t)(k0 + wc) * 2 + 8);
    float4 c3 = *(const float4*)(ckb + (size_t)(k0 + wc) * 2 + 12);
    int   am[8] = {am0.x, am0.y, am0.z, am0.w, am1.x, am1.y, am1.z, am1.w};
    int   al[8] = {al0.x, al0.y, al0.z, al0.w, al1.x, al1.y, al1.z, al1.w};
    float kx[8] = {c0.x, c0.z, c1.x, c1.z, c2.x, c2.z, c3.x, c3.z};
    float ky[8] = {c0.y, c0.w, c1.y, c1.w, c2.y, c2.w, c3.y, c3.w};
    bf16x8 w8;
#pragma unroll
    for (int j = 0; j < 8; j++) {
      float dx = qx - kx[j], dy = qy - ky[j];
      float sd = al[j] ? 0.f : sqrtf(dx * dx + dy * dy) * bs;
      float w = am[j] ? 0.f : (__expf((float)s8[j]) * inv - sd);
      w8[j] = (__bf16)w;
    }
    __syncthreads();                 // prev-iter frag reads done
    *(bf16x8*)&Ws[wr][wc] = w8;      // ds_write
#pragma unroll
    for (int h = 0; h < 8; h++)      // wave stages its own 128 fv rows
      g2l16(Vb + (size_t)(h * 16 + srow) * KN + k0 + scol, &Vs[wave * 128 + h * 16][0]);
    __syncthreads();                 // lgkm + vmcnt drain
    bf16x8 af[4];
#pragma unroll
    for (int i = 0; i < 4; i++) af[i] = *(bf16x8*)&Ws[i * 16 + r][quad * 8];
#pragma unroll
    for (int j = 0; j < 8; j++) {
      bf16x8 bfv = *(bf16x8*)&Vs[wave * 128 + j * 16 + r][quad * 8];
#pragma unroll
      for (int i = 0; i < 4; i++)
        acc[i][j] = __builtin_amdgcn_mfma_f32_16x16x32_bf16(af[i], bfv, acc[i][j], 0, 0, 0);
    }
  }
  // epilogue: row = q (quad*4+t), col = fv (lane&15)
#pragma unroll
  for (int i = 0; i < 4; i++)
#pragma unroll
    for (int j = 0; j < 8; j++)
#pragma unroll
      for (int t = 0; t < 4; t++) {
        int qq = q0 + qt + i * 16 + quad * 4 + t;
        int fv = wave * 128 + j * 16 + r;
        out[((size_t)b * QN + qq) * FVN + fv] = acc[i][j][t];
      }
}

// ---------------------------------------------------------------------------
extern "C" void kernel_launch(void* const* d_in, const int* in_sizes, int n_in,
                              void* d_out, int out_size, void* d_ws, size_t ws_size,
                              hipStream_t stream) {
  (void)in_sizes; (void)n_in; (void)out_size;
  const float* qm   = (const float*)d_in[0];
  const float* km   = (const float*)d_in[1];
  const float* vm   = (const float*)d_in[2];
  const float* cq   = (const float*)d_in[3];
  const float* ck   = (const float*)d_in[4];
  const int*   attn = (const int*)d_in[5];
  const int*   alibi= (const int*)d_in[6];
  const float* bsp  = (const float*)d_in[7];
  float* out = (float*)d_out;

  // ws layout: [qb][kb][Vt] fixed + [S: nb*qc*KN bf16][sums: nb*qc f32]
  __bf16* qb  = (__bf16*)d_ws;
  __bf16* kb  = qb + (size_t)BN * QN * FN;
  __bf16* Vt  = kb + (size_t)BN * KN * FN;
  const size_t fixed = ((size_t)BN * QN * FN + (size_t)BN * KN * FN +
                        (size_t)BN * FVN * KN) * 2;
  int nb = BN, qc = QN;
  while (nb > 1 && fixed + (size_t)nb * qc * (KN * 2 + 4) > ws_size) nb >>= 1;
  while (qc > 128 && fixed + (size_t)nb * qc * (KN * 2 + 4) > ws_size) qc >>= 1;
  __bf16* Sws  = Vt + (size_t)BN * FVN * KN;
  float*  sums = (float*)((char*)Sws + (size_t)nb * qc * KN * 2);

  prep<<<dim3((BN * QN * FN) / 2048, 3), 256, 0, stream>>>(qm, km, vm, qb, kb, Vt);
  for (int b0 = 0; b0 < BN; b0 += nb) {
    for (int q0 = 0; q0 < QN; q0 += qc) {
      hipMemsetAsync(sums, 0, (size_t)nb * qc * 4, stream);
      gemm_s<<<dim3(qc / 128, KN / 128, nb), 256, 0, stream>>>(qb, kb, Sws, sums, b0, q0, qc);
      gemm_wv<<<dim3(qc / 64, 1, nb), 256, 0, stream>>>(Sws, sums, Vt, cq, ck,
                                                        attn, alibi, bsp, out, b0, q0, qc);
    }
  }
}

// Round 6
// 514.453 us; speedup vs baseline: 1.0409x; 1.0409x over previous
//
#include <hip/hip_runtime.h>
#include <hip/hip_bf16.h>
#include <math.h>

// Problem constants (from reference setup_inputs)
#define BN  8
#define QN  2048
#define KN  2048
#define FN  512
#define FVN 512

typedef __bf16 bf16x8 __attribute__((ext_vector_type(8)));
typedef __bf16 bf16x4v __attribute__((ext_vector_type(4)));
typedef __bf16 bf16x2v __attribute__((ext_vector_type(2)));
typedef float  f32x4  __attribute__((ext_vector_type(4)));

__device__ inline bf16x8 pack8(float4 a, float4 b) {
  bf16x8 r;
  r[0] = (__bf16)a.x; r[1] = (__bf16)a.y; r[2] = (__bf16)a.z; r[3] = (__bf16)a.w;
  r[4] = (__bf16)b.x; r[5] = (__bf16)b.y; r[6] = (__bf16)b.z; r[7] = (__bf16)b.w;
  return r;
}

// Async global->LDS, 16B/lane. LDS dest = wave-uniform base + lane*16 (m97).
__device__ __forceinline__ void g2l16(const __bf16* g, __bf16* l) {
  __builtin_amdgcn_global_load_lds(
      (const __attribute__((address_space(1))) void*)g,
      (__attribute__((address_space(3))) void*)l,
      16, 0, 0);
}

// ---------------------------------------------------------------------------
// Kernel 0 (prep): y==0 -> q convert (pre-scaled), y==1 -> k convert,
//                  y==2 -> v transpose to Vt[b, fv, k] bf16.
// ---------------------------------------------------------------------------
__global__ __launch_bounds__(256) void prep(
    const float* __restrict__ qm, const float* __restrict__ km,
    const float* __restrict__ vm,
    __bf16* __restrict__ qb, __bf16* __restrict__ kb, __bf16* __restrict__ Vt) {
  const int tid = threadIdx.x;
  if (blockIdx.y == 0) {
    const size_t idx = ((size_t)blockIdx.x * 256 + tid) * 8;
    const float scale = 0.044194173824159216f;  // 512^-0.5
    float4 a = *(const float4*)(qm + idx);
    float4 b = *(const float4*)(qm + idx + 4);
    a.x *= scale; a.y *= scale; a.z *= scale; a.w *= scale;
    b.x *= scale; b.y *= scale; b.z *= scale; b.w *= scale;
    *(bf16x8*)(qb + idx) = pack8(a, b);
  } else if (blockIdx.y == 1) {
    const size_t idx = ((size_t)blockIdx.x * 256 + tid) * 8;
    float4 a = *(const float4*)(km + idx);
    float4 b = *(const float4*)(km + idx + 4);
    *(bf16x8*)(kb + idx) = pack8(a, b);
  } else {
    // v transpose: bx = ((b*8)+fblk)*32 + kblk
    const int bx = blockIdx.x;
    if (bx >= (KN / 64) * (FVN / 64) * BN) return;
    const int b  = bx >> 8;
    const int f0 = ((bx >> 5) & 7) * 64;
    const int k0 = (bx & 31) * 64;
    __shared__ float tile[64][65];
    const int r = tid >> 4;          // 0..15
    const int c = (tid & 15) * 4;    // 0..60
#pragma unroll
    for (int i = 0; i < 4; i++) {
      float4 u = *(const float4*)(vm + ((size_t)b * KN + k0 + r + i * 16) * FVN + f0 + c);
      tile[r + i * 16][c] = u.x; tile[r + i * 16][c + 1] = u.y;
      tile[r + i * 16][c + 2] = u.z; tile[r + i * 16][c + 3] = u.w;
    }
    __syncthreads();
#pragma unroll
    for (int i = 0; i < 4; i++) {
      int fv = r + i * 16;
      bf16x4v w;
      w[0] = (__bf16)tile[c][fv];     w[1] = (__bf16)tile[c + 1][fv];
      w[2] = (__bf16)tile[c + 2][fv]; w[3] = (__bf16)tile[c + 3][fv];
      *(bf16x4v*)(Vt + ((size_t)b * FVN + f0 + fv) * KN + k0 + c) = w;
    }
  }
}

// ---------------------------------------------------------------------------
// Kernel 1: S[z,q,k] = (bf16) dot(qb[b,q,:], kb[b,k,:])   (scale pre-folded)
// 128x128 tile, BK=64 (two [128][32] LDS half-tiles, g2l16 staging).
// Epilogue: per-row partial sum_k exp(bf16(S)) -> atomicAdd into sums.
// ---------------------------------------------------------------------------
__global__ __launch_bounds__(256) void gemm_s(
    const __bf16* __restrict__ qb, const __bf16* __restrict__ kb,
    __bf16* __restrict__ Sws, float* __restrict__ sums,
    int b0, int q0, int qchunk) {
  __shared__ __align__(16) __bf16 As[2][128][32];
  __shared__ __align__(16) __bf16 Bs[2][128][32];
  const int tid = threadIdx.x;
  const int lane = tid & 63, wave = tid >> 6;
  const int wq = (wave & 1) * 64, wk = (wave >> 1) * 64;
  const int qt = blockIdx.x * 128, kt = blockIdx.y * 128;
  const int z = blockIdx.z, b = b0 + z;
  __bf16* S = Sws + (size_t)z * qchunk * KN;
  const __bf16* Ab = qb + ((size_t)b * QN + q0 + qt) * FN;
  const __bf16* Bb = kb + ((size_t)b * KN + kt) * FN;
  const int srow = lane >> 2;         // 0..15 within 16-row group
  const int scol = (lane & 3) * 8;    // bf16 col within 32
  const int r = lane & 15, quad = lane >> 4;
  f32x4 acc[4][4] = {};
  for (int f0 = 0; f0 < FN; f0 += 64) {
    __syncthreads();
#pragma unroll
    for (int h = 0; h < 2; h++) {
      const int co = f0 + h * 32 + scol;
      g2l16(Ab + (size_t)(wave * 32 + srow) * FN + co,      &As[h][wave * 32][0]);
      g2l16(Ab + (size_t)(wave * 32 + 16 + srow) * FN + co, &As[h][wave * 32 + 16][0]);
      g2l16(Bb + (size_t)(wave * 32 + srow) * FN + co,      &Bs[h][wave * 32][0]);
      g2l16(Bb + (size_t)(wave * 32 + 16 + srow) * FN + co, &Bs[h][wave * 32 + 16][0]);
    }
    __syncthreads();
#pragma unroll
    for (int h = 0; h < 2; h++) {
      bf16x8 af[4], bf[4];
#pragma unroll
      for (int i = 0; i < 4; i++) af[i] = *(bf16x8*)&As[h][wq + i * 16 + r][quad * 8];
#pragma unroll
      for (int j = 0; j < 4; j++) bf[j] = *(bf16x8*)&Bs[h][wk + j * 16 + r][quad * 8];
#pragma unroll
      for (int i = 0; i < 4; i++)
#pragma unroll
        for (int j = 0; j < 4; j++)
          acc[i][j] = __builtin_amdgcn_mfma_f32_16x16x32_bf16(af[i], bf[j], acc[i][j], 0, 0, 0);
    }
  }
  // C/D layout: col = lane&15 (=k), row = quad*4+reg (=q). Write S (bf16) and
  // accumulate per-row sum of exp over this block's 64 k-columns (wave-local).
#pragma unroll
  for (int i = 0; i < 4; i++)
#pragma unroll
    for (int t = 0; t < 4; t++) {
      float e = 0.f;
#pragma unroll
      for (int j = 0; j < 4; j++) {
        __bf16 sb = (__bf16)acc[i][j][t];
        S[(size_t)(qt + wq + i * 16 + quad * 4 + t) * KN + (kt + wk + j * 16 + r)] = sb;
        e += __expf((float)sb);
      }
      // reduce over r (lanes sharing same row within the quad)
      e += __shfl_xor(e, 1); e += __shfl_xor(e, 2);
      e += __shfl_xor(e, 4); e += __shfl_xor(e, 8);
      if (r == 0)
        atomicAdd(&sums[(size_t)z * qchunk + qt + wq + i * 16 + quad * 4 + t], e);
    }
}

// ---------------------------------------------------------------------------
// Kernel 2 (fused): out[b,q,fv] = sum_k W[q,k] * Vt[fv,k]
//   W = attn ? 0 : (exp(S)/sums[q] - (alibi ? 0 : dist(q,k)*bias_scale))
// Block = 32q x 512fv, 512 threads (8 waves), BK=32.
// Grid (qc/32,1,nb) = 512 blocks -> 2 blocks/CU, 16 waves/CU (R5 was 4/CU).
// Wave w owns fv [w*64, w*64+64); each thread computes 2 W entries/iter.
// Masks/S read exactly once; W never touches HBM.
// ---------------------------------------------------------------------------
__global__ __launch_bounds__(512) void gemm_wv(
    const __bf16* __restrict__ S, const float* __restrict__ sums,
    const __bf16* __restrict__ Vt,
    const float* __restrict__ cq, const float* __restrict__ ck,
    const int* __restrict__ attn, const int* __restrict__ alibi,
    const float* __restrict__ bsp, float* __restrict__ out,
    int b0, int q0, int qchunk) {
  __shared__ __align__(16) __bf16 Ws[32][32];    // [q][k]   2 KB
  __shared__ __align__(16) __bf16 Vs[512][32];   // [fv][k] 32 KB
  const int tid = threadIdx.x;
  const int lane = tid & 63, wave = tid >> 6;
  const int qt = blockIdx.x * 32;
  const int z = blockIdx.z, b = b0 + z;
  const int wr = tid >> 4;          // W row 0..31 (q local)
  const int wc = (tid & 15) * 2;    // W col pair (k offset in tile)
  const int qg = q0 + qt + wr;
  const float qx = cq[((size_t)b * QN + qg) * 2 + 0];
  const float qy = cq[((size_t)b * QN + qg) * 2 + 1];
  const float inv = 1.0f / sums[(size_t)z * qchunk + qt + wr];
  const float bs = bsp[0];
  const __bf16* Srow = S + ((size_t)z * qchunk + qt + wr) * KN;
  const int* arow = attn + ((size_t)b * QN + qg) * KN;
  const int* lrow = alibi + ((size_t)b * QN + qg) * KN;
  const float* ckb = ck + (size_t)b * KN * 2;
  const __bf16* Vb = Vt + (size_t)b * FVN * KN;
  const int srow = lane >> 2, scol = (lane & 3) * 8;
  const int r = lane & 15, quad = lane >> 4;
  f32x4 acc[2][4] = {};
  for (int k0 = 0; k0 < KN; k0 += 32) {
    // --- W ingredients (issued before barrier: overlap prev MFMA phase) ---
    bf16x2v s2 = *(const bf16x2v*)(Srow + k0 + wc);
    int2 am2 = *(const int2*)(arow + k0 + wc);
    int2 al2 = *(const int2*)(lrow + k0 + wc);
    float4 cc = *(const float4*)(ckb + (size_t)(k0 + wc) * 2);  // x0,y0,x1,y1
    float w0, w1;
    {
      float dx = qx - cc.x, dy = qy - cc.y;
      float sd = al2.x ? 0.f : sqrtf(dx * dx + dy * dy) * bs;
      w0 = am2.x ? 0.f : (__expf((float)s2[0]) * inv - sd);
      dx = qx - cc.z; dy = qy - cc.w;
      sd = al2.y ? 0.f : sqrtf(dx * dx + dy * dy) * bs;
      w1 = am2.y ? 0.f : (__expf((float)s2[1]) * inv - sd);
    }
    bf16x2v w2; w2[0] = (__bf16)w0; w2[1] = (__bf16)w1;
    __syncthreads();                 // prev-iter frag reads done
    *(bf16x2v*)&Ws[wr][wc] = w2;     // ds_write_b32
#pragma unroll
    for (int h = 0; h < 4; h++)      // wave stages its own 64 fv rows
      g2l16(Vb + (size_t)(wave * 64 + h * 16 + srow) * KN + k0 + scol,
            &Vs[wave * 64 + h * 16][0]);
    __syncthreads();                 // lgkm + vmcnt drain
    bf16x8 af[2];
#pragma unroll
    for (int i = 0; i < 2; i++) af[i] = *(bf16x8*)&Ws[i * 16 + r][quad * 8];
#pragma unroll
    for (int j = 0; j < 4; j++) {
      bf16x8 bfv = *(bf16x8*)&Vs[wave * 64 + j * 16 + r][quad * 8];
#pragma unroll
      for (int i = 0; i < 2; i++)
        acc[i][j] = __builtin_amdgcn_mfma_f32_16x16x32_bf16(af[i], bfv, acc[i][j], 0, 0, 0);
    }
  }
  // epilogue: row = q (quad*4+t), col = fv (lane&15)
#pragma unroll
  for (int i = 0; i < 2; i++)
#pragma unroll
    for (int j = 0; j < 4; j++)
#pragma unroll
      for (int t = 0; t < 4; t++) {
        int qq = q0 + qt + i * 16 + quad * 4 + t;
        int fv = wave * 64 + j * 16 + r;
        out[((size_t)b * QN + qq) * FVN + fv] = acc[i][j][t];
      }
}

// ---------------------------------------------------------------------------
extern "C" void kernel_launch(void* const* d_in, const int* in_sizes, int n_in,
                              void* d_out, int out_size, void* d_ws, size_t ws_size,
                              hipStream_t stream) {
  (void)in_sizes; (void)n_in; (void)out_size;
  const float* qm   = (const float*)d_in[0];
  const float* km   = (const float*)d_in[1];
  const float* vm   = (const float*)d_in[2];
  const float* cq   = (const float*)d_in[3];
  const float* ck   = (const float*)d_in[4];
  const int*   attn = (const int*)d_in[5];
  const int*   alibi= (const int*)d_in[6];
  const float* bsp  = (const float*)d_in[7];
  float* out = (float*)d_out;

  // ws layout: [qb][kb][Vt] fixed + [S: nb*qc*KN bf16][sums: nb*qc f32]
  __bf16* qb  = (__bf16*)d_ws;
  __bf16* kb  = qb + (size_t)BN * QN * FN;
  __bf16* Vt  = kb + (size_t)BN * KN * FN;
  const size_t fixed = ((size_t)BN * QN * FN + (size_t)BN * KN * FN +
                        (size_t)BN * FVN * KN) * 2;
  int nb = BN, qc = QN;
  while (nb > 1 && fixed + (size_t)nb * qc * (KN * 2 + 4) > ws_size) nb >>= 1;
  while (qc > 128 && fixed + (size_t)nb * qc * (KN * 2 + 4) > ws_size) qc >>= 1;
  __bf16* Sws  = Vt + (size_t)BN * FVN * KN;
  float*  sums = (float*)((char*)Sws + (size_t)nb * qc * KN * 2);

  prep<<<dim3((BN * QN * FN) / 2048, 3), 256, 0, stream>>>(qm, km, vm, qb, kb, Vt);
  for (int b0 = 0; b0 < BN; b0 += nb) {
    for (int q0 = 0; q0 < QN; q0 += qc) {
      hipMemsetAsync(sums, 0, (size_t)nb * qc * 4, stream);
      gemm_s<<<dim3(qc / 128, KN / 128, nb), 256, 0, stream>>>(qb, kb, Sws, sums, b0, q0, qc);
      gemm_wv<<<dim3(qc / 32, 1, nb), 512, 0, stream>>>(Sws, sums, Vt, cq, ck,
                                                        attn, alibi, bsp, out, b0, q0, qc);
    }
  }
}